// Round 8
// baseline (504.729 us; speedup 1.0000x reference)
//
#include <hip/hip_runtime.h>

// CausalConv1d — round 8: resubmit of the DIAGNOSTIC (rounds 5-7 died to
// infra failures: container crash, then 2x GPU acquisition timeout — the
// kernel never executed). Identical body to round 4, executed nrep=2 times
// inside one dispatch so the kernel (~270us) exceeds the harness poison
// fills (~165us) and surfaces in the rocprof top-5 with its own FETCH_SIZE/
// WRITE_SIZE/VALUBusy/Occupancy/LDS-conflict counters. nt loads+stores mean
// pass 2 re-streams HBM -> per-pass traffic = total/2. dur_us will regress
// this round; the counters pay for the next rounds.

#define CC_H 4096
#define CC_B 4096
#define BLOCK 256
#define EPB (BLOCK * 4)          // flat elements per block
#define PLANE 257                // 256 + 1 vector pad per plane

typedef float f32x4 __attribute__((ext_vector_type(4)));

__global__ __launch_bounds__(BLOCK) void causal_conv1d_kernel(
    const float* __restrict__ x,        // B*H
    const float* __restrict__ state,    // B*H*3
    const float* __restrict__ weight,   // H*4
    const float* __restrict__ bias,     // H
    float* __restrict__ out,            // B*H
    float* __restrict__ new_state,      // B*H*3
    int nrep)                           // runtime 2: diagnostic repetition
{
    __shared__ f32x4 lds[3 * PLANE];    // 12.3 KB

    const int tid = threadIdx.x;
    const long long base_e  = (long long)blockIdx.x * EPB;
    const long long base_x4 = base_e >> 2;
    const long long base_s4 = (base_e * 3) >> 2;

    const f32x4* stateV = reinterpret_cast<const f32x4*>(state);
    const f32x4* xV     = reinterpret_cast<const f32x4*>(x);

    const int h0 = (int)(base_e & (CC_H - 1)) + tid * 4;
    const f32x4* wp = reinterpret_cast<const f32x4*>(weight + (long long)h0 * 4);
    const f32x4 bv = *reinterpret_cast<const f32x4*>(bias + h0);

    #pragma clang loop unroll(disable)
    for (int rep = 0; rep < nrep; ++rep) {
        asm volatile("" ::: "memory");   // forbid cross-rep load CSE
        __syncthreads();                 // WAR guard on lds across reps

        // ---- stage state: contiguous global (nt) -> transposed LDS planes ----
        #pragma unroll
        for (int i = 0; i < 3; ++i) {
            const int j = i * BLOCK + tid;          // 0..767
            const int t = j / 3;
            const int s = j - t * 3;
            lds[s * PLANE + t] = __builtin_nontemporal_load(&stateV[base_s4 + j]);
        }

        const f32x4 w0 = wp[0], w1 = wp[1], w2 = wp[2], w3 = wp[3];
        const f32x4 xv = __builtin_nontemporal_load(&xV[base_x4 + tid]);

        __syncthreads();

        const f32x4 s0 = lds[0 * PLANE + tid];   // f0  f1  f2  f3
        const f32x4 s1 = lds[1 * PLANE + tid];   // f4  f5  f6  f7
        const f32x4 s2 = lds[2 * PLANE + tid];   // f8  f9  f10 f11

        f32x4 o;
        o.x = fmaf(s0.x, w0.x, fmaf(s0.y, w0.y, fmaf(s0.z, w0.z, fmaf(xv.x, w0.w, bv.x))));
        o.y = fmaf(s0.w, w1.x, fmaf(s1.x, w1.y, fmaf(s1.y, w1.z, fmaf(xv.y, w1.w, bv.y))));
        o.z = fmaf(s1.z, w2.x, fmaf(s1.w, w2.y, fmaf(s2.x, w2.z, fmaf(xv.z, w2.w, bv.z))));
        o.w = fmaf(s2.y, w3.x, fmaf(s2.z, w3.y, fmaf(s2.w, w3.z, fmaf(xv.w, w3.w, bv.w))));
        __builtin_nontemporal_store(o, &reinterpret_cast<f32x4*>(out)[base_x4 + tid]);

        // ---- new_state permutation: f1 f2 x0 | f4 f5 x1 | f7 f8 x2 | f10 f11 x3 ----
        f32x4 n0, n1, n2;
        n0.x = s0.y; n0.y = s0.z; n0.z = xv.x; n0.w = s1.x;
        n1.x = s1.y; n1.y = xv.y; n1.z = s1.w; n1.w = s2.x;
        n2.x = xv.z; n2.y = s2.z; n2.z = s2.w; n2.w = xv.w;

        lds[0 * PLANE + tid] = n0;
        lds[1 * PLANE + tid] = n1;
        lds[2 * PLANE + tid] = n2;

        __syncthreads();

        // ---- drain: transposed LDS planes -> contiguous global (nt) ----
        f32x4* nsV = reinterpret_cast<f32x4*>(new_state);
        #pragma unroll
        for (int i = 0; i < 3; ++i) {
            const int j = i * BLOCK + tid;
            const int t = j / 3;
            const int s = j - t * 3;
            __builtin_nontemporal_store(lds[s * PLANE + t], &nsV[base_s4 + j]);
        }
    }
}

extern "C" void kernel_launch(void* const* d_in, const int* in_sizes, int n_in,
                              void* d_out, int out_size, void* d_ws, size_t ws_size,
                              hipStream_t stream) {
    const float* x      = (const float*)d_in[0];
    const float* state  = (const float*)d_in[1];
    const float* weight = (const float*)d_in[2];
    const float* bias   = (const float*)d_in[3];

    const long long BH = (long long)CC_B * CC_H;
    float* out       = (float*)d_out;          // first B*H floats
    float* new_state = (float*)d_out + BH;     // next B*H*3 floats

    const int grid = (int)(BH / EPB);          // 16384 blocks
    causal_conv1d_kernel<<<grid, BLOCK, 0, stream>>>(x, state, weight, bias, out,
                                                     new_state, /*nrep=*/2);
}